// Round 11
// baseline (378.003 us; speedup 1.0000x reference)
//
#include <hip/hip_runtime.h>
#include <hip/hip_fp16.h>
#include <math.h>

#define BATCH 2048
#define NFEAT 7
#define CARD 10000
#define CONCAT 256
#define P_HID 512

#define BM 256
#define BN 256
#define BK 64
#define KSPLIT 16             // 16 splits x 40 units; grid 8x2x16 = 256 = 1/CU
#define NTILES 40
#define NUNITS 640            // triangle-packed (i, j-window) units
#define UNIT_ST (512 * 64)    // fp16 elements per unit in blocked St layout
#define PREP_BLOCKS (NUNITS * 2)   // one block per (unit, n-half)

using f16x4   = __attribute__((ext_vector_type(4))) _Float16;
using half8   = __attribute__((ext_vector_type(8))) _Float16;
using floatx4 = __attribute__((ext_vector_type(4))) float;

// async global->LDS DMA, 16 B per lane; LDS dest = wave-uniform base + lane*16
__device__ __forceinline__ void dma16(const _Float16* g, _Float16* l) {
    __builtin_amdgcn_global_load_lds(
        (const __attribute__((address_space(1))) unsigned int*)g,
        (__attribute__((address_space(3))) unsigned int*)l,
        16, 0, 0);
}

// unit u -> (i, jw): pairs (i, j) with j in [jw*64, jw*64+64).
// u<256: diagonal-window units, i=u, jw=i>>6 (entries j<i zeroed in B).
// u>=256: full units, ordered by i with jw > i>>6.
__device__ __forceinline__ void unit_decode(int u, int& i, int& jw) {
    if (u < 256)      { i = u;                jw = u >> 6; }
    else if (u < 448) { int v = u - 256; i = v / 3;        jw = 1 + v % 3; }
    else if (u < 576) { int v = u - 448; i = 64 + (v >> 1); jw = 2 + (v & 1); }
    else              { i = 128 + (u - 576); jw = 3; }
}

// ---------------------------------------------------------------------------
// Kernel 1 (fused pre): R4/R10 version, unchanged.
// ---------------------------------------------------------------------------
__global__ __launch_bounds__(256) void fused_pre(
    const float* __restrict__ dense, const int* __restrict__ sparse,
    const float* __restrict__ emb,
    const float* __restrict__ dw1, const float* __restrict__ db1,
    const float* __restrict__ dw2, const float* __restrict__ db2,
    const float* __restrict__ sw1, const float* __restrict__ sb1,
    const float* __restrict__ sw2, const float* __restrict__ sb2,
    const float* __restrict__ pw1,
    _Float16* __restrict__ cbf, _Float16* __restrict__ St)
{
    __shared__ __align__(16) _Float16 sh[64 * 256];   // 32 KB
    const int tid = threadIdx.x;

    if (blockIdx.x < PREP_BLOCKS) {
        const int u = blockIdx.x >> 1, nh = blockIdx.x & 1;
        const int nb = nh * 256;
        int i, jw;
        unit_decode(u, i, jw);

        // ---- fill: 64 q-rows x 256 n, fp32 sum -> fp16 in LDS ----
#pragma unroll
        for (int m = 0; m < 16; ++m) {
            const int flat = m * 256 + tid;       // [0, 4096)
            const int q = flat >> 6, c4 = flat & 63;
            const int j = (jw << 6) + q;
            floatx4 s = {0.f, 0.f, 0.f, 0.f};
            if (j >= i) {
                s = __builtin_nontemporal_load(
                    (const floatx4*)(pw1 + ((size_t)i * 256 + j) * P_HID + nb + 4 * c4));
                if (j > i) {
                    const floatx4 mv = __builtin_nontemporal_load(
                        (const floatx4*)(pw1 + ((size_t)j * 256 + i) * P_HID + nb + 4 * c4));
                    s += mv;
                }
            }
            f16x4 hv = {(_Float16)s.x, (_Float16)s.y, (_Float16)s.z, (_Float16)s.w};
            *(f16x4*)(sh + q * 256 + 4 * c4) = hv;   // conflict-free
        }
        __syncthreads();

        // ---- transpose + store: thread t owns n-column (nb + t) ----
        const _Float16* col = sh + tid;
        _Float16* outp = St + (size_t)u * UNIT_ST + (size_t)(nb + tid) * 64;
#pragma unroll
        for (int e = 0; e < 8; ++e) {
            half8 o;
#pragma unroll
            for (int r = 0; r < 8; ++r) o[r] = col[(8 * e + r) * 256];
            *(half8*)(outp + 8 * e) = o;
        }
    } else {
        // ---- concat build: 4 batch rows per block, one wave per row ----
        float* smem = (float*)sh;
        const int wv = tid >> 6, t = tid & 63;
        const int b = (blockIdx.x - PREP_BLOCKS) * 4 + wv;
        float* xs   = smem + wv * 13;
        float* bufA = smem + 64  + wv * 64;
        float* bufB = smem + 320 + wv * 64;

        if (t < 13) xs[t] = dense[b * 13 + t];
        __syncthreads();

        float h = db1[t];
#pragma unroll
        for (int d = 0; d < 13; ++d) h += xs[d] * dw1[d * 64 + t];
        bufA[t] = fmaxf(h, 0.f);
        __syncthreads();

        if (t < 32) {
            float o = db2[t];
#pragma unroll
            for (int k = 0; k < 64; ++k) o += bufA[k] * dw2[k * 32 + t];
            cbf[b * 256 + t] = (_Float16)o;
        }

        for (int f = 0; f < NFEAT; ++f) {
            __syncthreads();
            const int idx = sparse[b * NFEAT + f];
            bufB[t] = emb[((size_t)(f * CARD + idx)) * 64 + t];
            __syncthreads();
            float s = sb1[f * 64 + t];
#pragma unroll
            for (int e = 0; e < 64; ++e) s += bufB[e] * sw1[(f * 64 + e) * 64 + t];
            bufA[t] = fmaxf(s, 0.f);
            __syncthreads();
            if (t < 32) {
                float o = sb2[f * 32 + t];
#pragma unroll
                for (int k = 0; k < 64; ++k) o += bufA[k] * sw2[(f * 64 + k) * 32 + t];
                cbf[b * 256 + 32 + f * 32 + t] = (_Float16)o;
            }
        }
    }
}

// ---------------------------------------------------------------------------
// Kernel 2: hidden[b,n] = sum over packed pairs A[b,k] * St[n,k].
// fp16 GEMM M=2048 N=512 K=40960.
// R11: 256x256 tile, 8 waves (2Mx4N, 128x64 per wave), 1 block/CU.
// R10 post-mortem: nothing saturated (MFMA 37%, LDS 25%, VALU 24%) -> the
// 2-barrier/tile lockstep convoy is ~60% dead time (m97-structure ceiling).
// Fix: A AND B double-buffered in LDS (128 KB total) -> zero same-buffer
// hazards -> ONE s_barrier per tile, with counted vmcnt(1) (drains only
// dma(it+1), covered by a full MFMA phase) + lgkmcnt(0) (A-gen writes).
// A-gen(it+1) and dma(it+1) overlap MFMA(it) in the same phase.
// 4x FLOPs per barrier vs R10. acc 128 + pre 64 VGPR -> launch_bounds(512,2).
// ---------------------------------------------------------------------------
__global__ __launch_bounds__(512, 2) void bilinear_gemm(
    const _Float16* __restrict__ cbf, const _Float16* __restrict__ St,
    _Float16* __restrict__ hidpart)
{
    __shared__ __align__(16) _Float16 Albuf[2][BM * BK];   // 2 x 32 KB, XOR-swz
    __shared__ _Float16 Bl[2][BN][BK];                     // 2 x 32 KB, XOR-swz

    // XCD-aware decode (256 blocks, %8==0 -> bijective)
    const int b = blockIdx.x;
    const int xcd = b & 7, slot = b >> 3;        // slot 0..31
    const int mt = slot & 7;
    const int slice = ((slot >> 3) << 3) | xcd;  // 0..31
    const int nt = slice & 1, ks = slice >> 1;   // nt 0..1, ks 0..15
    const int m0 = mt * BM, n0 = nt * BN;
    const int t0 = ks * NTILES;

    const int tid = threadIdx.x, lane = tid & 63, wv = tid >> 6;
    const int wrow = (wv & 1) * 128, wcol = (wv >> 1) * 64;
    const int l15 = lane & 15, l4 = lane >> 4, l7 = lane & 7;
    const int arow = tid >> 1, ajoff = (tid & 1) * 32;  // A-gen: 2 thr/row

    floatx4 acc[8][4];
#pragma unroll
    for (int i = 0; i < 8; ++i)
#pragma unroll
        for (int j = 0; j < 4; ++j) acc[i][j] = (floatx4){0.f, 0.f, 0.f, 0.f};

    const _Float16* crow = cbf + (m0 + arow) * 256;

    // ---- hoisted window preload: all 4 possible jw windows (64 VGPR) ----
    half8 pre[4][4];
#pragma unroll
    for (int jw = 0; jw < 4; ++jw)
#pragma unroll
        for (int x = 0; x < 4; ++x)
            pre[jw][x] = *(const half8*)(crow + (jw << 6) + ajoff + 8 * x);

    const int awsz = (arow & 7) << 4;            // A XOR swizzle

    // B staging source (pre-swizzled per-lane global address, blocked St)
    const int drow = wv * 32 + (lane >> 3);
    const int eswz = (lane & 7) ^ ((lane >> 3) & 7);
    const _Float16* bsrc = St + (size_t)t0 * UNIT_ST + (size_t)(n0 + drow) * 64 + eswz * 8;

    // A-gen: pre[JW] * C -> Albuf[NB] (swizzled packed 128 B rows)
#define AGEN(NB, JW, C)                                                        \
    {                                                                          \
        const half8 civ_ = {C, C, C, C, C, C, C, C};                           \
        char* aw_ = (char*)Albuf[NB] + arow * 128;                             \
        *(half8*)(aw_ + ((ajoff * 2 +  0) ^ awsz)) = pre[JW][0] * civ_;        \
        *(half8*)(aw_ + ((ajoff * 2 + 16) ^ awsz)) = pre[JW][1] * civ_;        \
        *(half8*)(aw_ + ((ajoff * 2 + 32) ^ awsz)) = pre[JW][2] * civ_;        \
        *(half8*)(aw_ + ((ajoff * 2 + 48) ^ awsz)) = pre[JW][3] * civ_;        \
    }
#define AGEN_SW(NB, JW, C)                                                     \
    switch (JW) {                                                              \
        case 0:  AGEN(NB, 0, C); break;                                        \
        case 1:  AGEN(NB, 1, C); break;                                        \
        case 2:  AGEN(NB, 2, C); break;                                        \
        default: AGEN(NB, 3, C); break;                                        \
    }

    _Float16 ciA, ciB;

    // ---- prologue: build tile 0 (A[0], B[0]); load ci(1) ----
    {
        int ui0, ujw0; unit_decode(t0, ui0, ujw0);
        const _Float16 ci0 = crow[ui0];
#pragma unroll
        for (int p = 0; p < 4; ++p)
            dma16(bsrc + (size_t)(p * 8) * 64, &Bl[0][wv * 32 + p * 8][0]);
        bsrc += UNIT_ST;
        AGEN_SW(0, ujw0, ci0);
        int ui1, ujw1; unit_decode(t0 + 1, ui1, ujw1);
        ciA = crow[ui1];
    }
    asm volatile("s_waitcnt vmcnt(1) lgkmcnt(0)" ::: "memory");  // dma(0) done
    __builtin_amdgcn_s_barrier();
    __builtin_amdgcn_sched_barrier(0);

    // BODY(IT, CUR): stage tile IT+1 into buffers CUR^1 (A-gen uses CIC =
    // ci(IT+1)); load ci(IT+2) into CIN; MFMA(IT) on buffers CUR; counted
    // wait + single barrier. vm outstanding at wait: dma(IT+1) x4 + ci(IT+2).
#define GBODY(IT, CIC, CIN, CUR)                                               \
    {                                                                          \
        const int it_ = (IT);                                                  \
        if (it_ + 1 < NTILES) {                                                \
            _Pragma("unroll")                                                  \
            for (int p = 0; p < 4; ++p)                                        \
                dma16(bsrc + (size_t)(p * 8) * 64,                             \
                      &Bl[(CUR) ^ 1][wv * 32 + p * 8][0]);                     \
            bsrc += UNIT_ST;                                                   \
            int ujw1_, ui1_; unit_decode(t0 + it_ + 1, ui1_, ujw1_);           \
            AGEN_SW((CUR) ^ 1, ujw1_, CIC);                                    \
        }                                                                      \
        if (it_ + 2 < NTILES) {                                                \
            int ui2_, ujw2_; unit_decode(t0 + it_ + 2, ui2_, ujw2_);           \
            CIN = crow[ui2_];                                                  \
        }                                                                      \
        __builtin_amdgcn_s_setprio(1);                                         \
        _Pragma("unroll")                                                      \
        for (int kh = 0; kh < 2; ++kh) {                                       \
            half8 af[8], bfr[4];                                               \
            _Pragma("unroll")                                                  \
            for (int i = 0; i < 8; ++i) {                                      \
                const int r_ = wrow + i * 16 + l15;                            \
                const int cb_ = (kh * 64 + l4 * 16) ^ ((r_ & 7) << 4);         \
                af[i] = *(const half8*)((const char*)Albuf[CUR] + r_ * 128 + cb_); \
            }                                                                  \
            const int s_ = ((kh * 4 + l4) ^ l7) * 8;                           \
            _Pragma("unroll")                                                  \
            for (int j = 0; j < 4; ++j)                                        \
                bfr[j] = *(const half8*)&Bl[CUR][wcol + j * 16 + l15][s_];     \
            _Pragma("unroll")                                                  \
            for (int i = 0; i < 8; ++i)                                        \
                _Pragma("unroll")                                              \
                for (int j = 0; j < 4; ++j)                                    \
                    acc[i][j] = __builtin_amdgcn_mfma_f32_16x16x32_f16(        \
                        af[i], bfr[j], acc[i][j], 0, 0, 0);                    \
        }                                                                      \
        __builtin_amdgcn_s_setprio(0);                                         \
        if (it_ + 1 < NTILES) {                                                \
            if (it_ + 2 < NTILES)                                              \
                asm volatile("s_waitcnt vmcnt(1) lgkmcnt(0)" ::: "memory");    \
            else                                                               \
                asm volatile("s_waitcnt vmcnt(0) lgkmcnt(0)" ::: "memory");    \
            __builtin_amdgcn_s_barrier();                                      \
            __builtin_amdgcn_sched_barrier(0);                                 \
        }                                                                      \
    }

    for (int it2 = 0; it2 < NTILES; it2 += 2) {
        GBODY(it2,     ciA, ciB, 0);
        GBODY(it2 + 1, ciB, ciA, 1);
    }
#undef GBODY
#undef AGEN_SW
#undef AGEN

    // epilogue: C/D layout col=lane&15, row=(lane>>4)*4+r (m89-verified)
    _Float16* outp = hidpart + (size_t)ks * BATCH * P_HID;
    const int r0 = m0 + wrow + l4 * 4;
    const int c0 = n0 + wcol + l15;
#pragma unroll
    for (int i = 0; i < 8; ++i)
#pragma unroll
        for (int j = 0; j < 4; ++j)
#pragma unroll
            for (int r = 0; r < 4; ++r)
                outp[(size_t)(r0 + i * 16 + r) * P_HID + c0 + j * 16] =
                    (_Float16)acc[i][j][r];
}

// ---------------------------------------------------------------------------
// Kernel 3: sum k-splits + pb1, ReLU, dot with pw2, +pb2, sigmoid -> f32 out
// Coalesced half8 loads; waves split the 16 k-splits; LDS cross-wave reduce.
// ---------------------------------------------------------------------------
__global__ __launch_bounds__(256) void finalize(
    const _Float16* __restrict__ hidpart,
    const float* __restrict__ pb1,
    const float* __restrict__ pw2,
    const float* __restrict__ pb2,
    float* __restrict__ out)
{
    const int b = blockIdx.x, t = threadIdx.x;
    const int wv = t >> 6, lane = t & 63;

    float acc[8];
#pragma unroll
    for (int k = 0; k < 8; ++k) acc[k] = 0.f;

    // wave wv handles splits {wv, wv+4, wv+8, wv+12}; lane owns 8 consec n
#pragma unroll
    for (int si = 0; si < 4; ++si) {
        const int s = wv + 4 * si;
        const half8 v = *(const half8*)(hidpart + (size_t)s * BATCH * P_HID
                                        + (size_t)b * P_HID + lane * 8);
#pragma unroll
        for (int k = 0; k < 8; ++k) acc[k] += (float)v[k];
    }

    __shared__ float red[4 * 512];   // [wave][k*64+lane]
#pragma unroll
    for (int k = 0; k < 8; ++k) red[wv * 512 + k * 64 + lane] = acc[k];
    __syncthreads();

    if (wv == 0) {
        float dot = 0.f;
#pragma unroll
        for (int k = 0; k < 8; ++k) {
            const int n = lane * 8 + k;
            float v = red[k * 64 + lane] + red[512 + k * 64 + lane]
                    + red[1024 + k * 64 + lane] + red[1536 + k * 64 + lane];
            v += pb1[n];
            v = fmaxf(v, 0.f);
            dot += v * pw2[n];
        }
#pragma unroll
        for (int off = 32; off; off >>= 1) dot += __shfl_down(dot, off, 64);
        if (lane == 0) {
            const float s = dot + pb2[0];
            out[b] = 1.f / (1.f + expf(-s));
        }
    }
}

extern "C" void kernel_launch(void* const* d_in, const int* in_sizes, int n_in,
                              void* d_out, int out_size, void* d_ws, size_t ws_size,
                              hipStream_t stream)
{
    const float* dense  = (const float*)d_in[0];
    const int*   sparse = (const int*)d_in[1];
    // d_in[2] tokenizers == arange(CARD): gather index is the sparse value itself
    const float* emb = (const float*)d_in[3];
    const float* dw1 = (const float*)d_in[4];
    const float* db1 = (const float*)d_in[5];
    const float* dw2 = (const float*)d_in[6];
    const float* db2 = (const float*)d_in[7];
    const float* sw1 = (const float*)d_in[8];
    const float* sb1 = (const float*)d_in[9];
    const float* sw2 = (const float*)d_in[10];
    const float* sb2 = (const float*)d_in[11];
    const float* pw1 = (const float*)d_in[12];
    const float* pb1 = (const float*)d_in[13];
    const float* pw2 = (const float*)d_in[14];
    const float* pb2 = (const float*)d_in[15];

    char* ws = (char*)d_ws;
    _Float16* cbf     = (_Float16*)ws;                                   // 1 MB
    _Float16* St      = (_Float16*)(ws + (1 << 20));                     // 40 MB
    _Float16* hidpart = (_Float16*)(ws + (1 << 20) + ((size_t)40 << 20)); // 32 MB (16 splits)

    fused_pre<<<PREP_BLOCKS + BATCH / 4, 256, 0, stream>>>(
        dense, sparse, emb, dw1, db1, dw2, db2, sw1, sb1, sw2, sb2, pw1,
        cbf, St);
    bilinear_gemm<<<8 * 2 * KSPLIT, 512, 0, stream>>>(cbf, St, hidpart);
    finalize<<<BATCH, 256, 0, stream>>>(hidpart, pb1, pw2, pb2, (float*)d_out);
}

// Round 12
// 354.728 us; speedup vs baseline: 1.0656x; 1.0656x over previous
//
#include <hip/hip_runtime.h>
#include <hip/hip_fp16.h>
#include <math.h>

#define BATCH 2048
#define NFEAT 7
#define CARD 10000
#define CONCAT 256
#define P_HID 512

#define BM 128
#define BN 128
#define BK 64
#define KSPLIT 12             // 768 blocks = exactly 3 per CU (launch_bounds 3)
#define NUNITS 640            // triangle-packed (i, j-window) units
#define UNIT_ST (512 * 64)    // fp16 elements per unit in blocked St layout
#define PREP_BLOCKS (NUNITS * 2)   // one block per (unit, n-half)

using f16x4   = __attribute__((ext_vector_type(4))) _Float16;
using half8   = __attribute__((ext_vector_type(8))) _Float16;
using floatx4 = __attribute__((ext_vector_type(4))) float;

// async global->LDS DMA, 16 B per lane; LDS dest = wave-uniform base + lane*16
__device__ __forceinline__ void dma16(const _Float16* g, _Float16* l) {
    __builtin_amdgcn_global_load_lds(
        (const __attribute__((address_space(1))) unsigned int*)g,
        (__attribute__((address_space(3))) unsigned int*)l,
        16, 0, 0);
}

// unit u -> (i, jw): pairs (i, j) with j in [jw*64, jw*64+64).
// u<256: diagonal-window units, i=u, jw=i>>6 (entries j<i zeroed in B).
// u>=256: full units, ordered by i with jw > i>>6.
__device__ __forceinline__ void unit_decode(int u, int& i, int& jw) {
    if (u < 256)      { i = u;                jw = u >> 6; }
    else if (u < 448) { int v = u - 256; i = v / 3;        jw = 1 + v % 3; }
    else if (u < 576) { int v = u - 448; i = 64 + (v >> 1); jw = 2 + (v & 1); }
    else              { i = 128 + (u - 576); jw = 3; }
}

// ks-split ranges over units: 640 = 4*54 + 8*53
__device__ __forceinline__ int split_t0(int ks)     { return ks * 53 + (ks < 4 ? ks : 4); }
__device__ __forceinline__ int split_ntiles(int ks) { return 53 + (ks < 4 ? 1 : 0); }

// ---------------------------------------------------------------------------
// Kernel 1 (fused pre):
//  blockIdx < PREP_BLOCKS: symmetrized B-prep, one block per (unit, n-half).
//    R12: fill loop BATCHED — 8 m-iters of (upper, mirror) loads staged in
//    registers (16 loads in flight/thread; old code compiled to VGPR=40 ->
//    ~2 in flight -> latency-bound with nothing busy). NT hints dropped
//    (R0 FETCH=66MB<134MB showed L3 serves pw1 regardless — let it help).
//  blockIdx >= PREP_BLOCKS: dense MLP + gather + sparse MLPs -> concat fp16.
//  tokenizers == arange(CARD) -> gather index is the sparse value itself.
// ---------------------------------------------------------------------------
__global__ __launch_bounds__(256) void fused_pre(
    const float* __restrict__ dense, const int* __restrict__ sparse,
    const float* __restrict__ emb,
    const float* __restrict__ dw1, const float* __restrict__ db1,
    const float* __restrict__ dw2, const float* __restrict__ db2,
    const float* __restrict__ sw1, const float* __restrict__ sb1,
    const float* __restrict__ sw2, const float* __restrict__ sb2,
    const float* __restrict__ pw1,
    _Float16* __restrict__ cbf, _Float16* __restrict__ St)
{
    __shared__ __align__(16) _Float16 sh[64 * 256];   // 32 KB
    const int tid = threadIdx.x;

    if (blockIdx.x < PREP_BLOCKS) {
        const int u = blockIdx.x >> 1, nh = blockIdx.x & 1;
        const int nb = nh * 256;
        int i, jw;
        unit_decode(u, i, jw);

        // ---- fill: 64 q-rows x 256 n, fp32 sum -> fp16 in LDS ----
        // two batches of 8 m-iters; 16 float4 loads in flight per thread.
        floatx4 ua[8], va[8];
#pragma unroll
        for (int g = 0; g < 2; ++g) {
            // issue all loads of this batch (wave-uniform branch: q uniform)
#pragma unroll
            for (int mm = 0; mm < 8; ++mm) {
                const int flat = (g * 8 + mm) * 256 + tid;   // [0, 4096)
                const int q = flat >> 6, c4 = flat & 63;
                const int j = (jw << 6) + q;
                ua[mm] = (floatx4){0.f, 0.f, 0.f, 0.f};
                va[mm] = (floatx4){0.f, 0.f, 0.f, 0.f};
                if (j >= i) {
                    ua[mm] = *(const floatx4*)(pw1 + ((size_t)i * 256 + j) * P_HID + nb + 4 * c4);
                    if (j > i)
                        va[mm] = *(const floatx4*)(pw1 + ((size_t)j * 256 + i) * P_HID + nb + 4 * c4);
                }
            }
            // convert + store batch
#pragma unroll
            for (int mm = 0; mm < 8; ++mm) {
                const int flat = (g * 8 + mm) * 256 + tid;
                const int q = flat >> 6, c4 = flat & 63;
                const floatx4 s = ua[mm] + va[mm];
                f16x4 hv = {(_Float16)s.x, (_Float16)s.y, (_Float16)s.z, (_Float16)s.w};
                *(f16x4*)(sh + q * 256 + 4 * c4) = hv;   // conflict-free
            }
        }
        __syncthreads();

        // ---- transpose + store: thread t owns n-column (nb + t) ----
        const _Float16* col = sh + tid;
        _Float16* outp = St + (size_t)u * UNIT_ST + (size_t)(nb + tid) * 64;
#pragma unroll
        for (int e = 0; e < 8; ++e) {
            half8 o;
#pragma unroll
            for (int r = 0; r < 8; ++r) o[r] = col[(8 * e + r) * 256];
            *(half8*)(outp + 8 * e) = o;
        }
    } else {
        // ---- concat build: 4 batch rows per block, one wave per row ----
        float* smem = (float*)sh;
        const int wv = tid >> 6, t = tid & 63;
        const int b = (blockIdx.x - PREP_BLOCKS) * 4 + wv;
        float* xs   = smem + wv * 13;
        float* bufA = smem + 64  + wv * 64;
        float* bufB = smem + 320 + wv * 64;

        if (t < 13) xs[t] = dense[b * 13 + t];
        __syncthreads();

        float h = db1[t];
#pragma unroll
        for (int d = 0; d < 13; ++d) h += xs[d] * dw1[d * 64 + t];
        bufA[t] = fmaxf(h, 0.f);
        __syncthreads();

        if (t < 32) {
            float o = db2[t];
#pragma unroll
            for (int k = 0; k < 64; ++k) o += bufA[k] * dw2[k * 32 + t];
            cbf[b * 256 + t] = (_Float16)o;
        }

        for (int f = 0; f < NFEAT; ++f) {
            __syncthreads();
            const int idx = sparse[b * NFEAT + f];
            bufB[t] = emb[((size_t)(f * CARD + idx)) * 64 + t];
            __syncthreads();
            float s = sb1[f * 64 + t];
#pragma unroll
            for (int e = 0; e < 64; ++e) s += bufB[e] * sw1[(f * 64 + e) * 64 + t];
            bufA[t] = fmaxf(s, 0.f);
            __syncthreads();
            if (t < 32) {
                float o = sb2[f * 32 + t];
#pragma unroll
                for (int k = 0; k < 64; ++k) o += bufA[k] * sw2[(f * 64 + k) * 32 + t];
                cbf[b * 256 + 32 + f * 32 + t] = (_Float16)o;
            }
        }
    }
}

// ---------------------------------------------------------------------------
// Kernel 2: hidden[b,n] = sum over packed pairs A[b,k] * St[n,k].
// fp16 GEMM M=2048 N=512 K=40960.
// R12 = R10/R8 verbatim (measured best twice: 98.1-98.7 us, MfmaUtil 38%,
// conflicts 0). LDS A-gen from hoisted pre[4][4]; B double-buffered with
// counted vmcnt(5); A packed [128][64] XOR-swizzled; 3 blocks/CU.
// Refuted neighbors: register-A (R3/R7/R9: TA-bound), 256^2 1-block/CU
// (R11: exposure — no cross-block TLP). LDS port ~76% busy in this
// structure (288KB per 1478-cyc CU-round) -> its ceiling is ~80 us.
// ---------------------------------------------------------------------------
__global__ __launch_bounds__(256, 3) void bilinear_gemm(
    const _Float16* __restrict__ cbf, const _Float16* __restrict__ St,
    _Float16* __restrict__ hidpart)
{
    __shared__ __align__(16) _Float16 Al[BM * BK];   // 16 KB packed, XOR-swizzled
    __shared__ _Float16 Bl[2][BN][BK];               // 2 x 16 KB, XOR-swizzled

    // XCD-aware decode: 16 m-blocks of one (nt,ks) slice share one XCD's L2.
    const int b = blockIdx.x;               // 768 blocks, 768%8==0 -> bijective
    const int xcd = b & 7, slot = b >> 3;
    const int mt = slot & 15;
    const int slice = ((slot >> 4) << 3) | xcd;   // 0..47
    const int nt = slice & 3, ks = slice >> 2;    // ks in 0..11
    const int m0 = mt * BM, n0 = nt * BN;
    const int t0 = split_t0(ks);
    const int ntiles = split_ntiles(ks);

    const int tid = threadIdx.x, lane = tid & 63, wv = tid >> 6;
    const int wrow = (wv & 1) * 64, wcol = (wv >> 1) * 64;
    const int l15 = lane & 15, l4 = lane >> 4, l7 = lane & 7;
    const int arow = tid >> 1, ajoff = (tid & 1) * 32;  // A-gen: 2 thr/row

    floatx4 acc[4][4];
#pragma unroll
    for (int i = 0; i < 4; ++i)
#pragma unroll
        for (int j = 0; j < 4; ++j) acc[i][j] = (floatx4){0.f, 0.f, 0.f, 0.f};

    const _Float16* crow = cbf + (m0 + arow) * 256;

    // ---- hoisted window preload: all 4 possible jw windows (64 VGPR) ----
    half8 pre[4][4];
#pragma unroll
    for (int jw = 0; jw < 4; ++jw)
#pragma unroll
        for (int x = 0; x < 4; ++x)
            pre[jw][x] = *(const half8*)(crow + (jw << 6) + ajoff + 8 * x);

    // A-gen write base (XOR-swizzled packed rows, 128 B each)
    char* awbase = (char*)Al + arow * 128;
    const int awsz = (arow & 7) << 4;

    // B staging source (pre-swizzled per-lane global address, blocked St)
    const int drow = wv * 32 + (lane >> 3);
    const int eswz = (lane & 7) ^ ((lane >> 3) & 7);
    const _Float16* bsrc = St + (size_t)t0 * UNIT_ST + (size_t)(n0 + drow) * 64 + eswz * 8;

    // ---- prologue: tile-0 decode + ci, stage tile 0 into Bl[0] ----
    int ui_c, ujw_c;
    unit_decode(t0, ui_c, ujw_c);
    _Float16 ci_c = crow[ui_c];
#pragma unroll
    for (int p = 0; p < 4; ++p)
        dma16(bsrc + (size_t)(p * 8) * 64, &Bl[0][wv * 32 + p * 8][0]);
    bsrc += UNIT_ST;

    for (int it = 0; it < ntiles; ++it) {
        const int cur = it & 1;
        const bool more = (it + 1 < ntiles);

        // ---- issue next tile's B DMA into the other buffer ----
        if (more) {
#pragma unroll
            for (int p = 0; p < 4; ++p)
                dma16(bsrc + (size_t)(p * 8) * 64, &Bl[cur ^ 1][wv * 32 + p * 8][0]);
            bsrc += UNIT_ST;
        }

        // ---- A-gen(it): pre[ujw] * ci -> swizzled LDS (covers DMA issue) ----
        {
            const half8 civ = {ci_c, ci_c, ci_c, ci_c, ci_c, ci_c, ci_c, ci_c};
#define AGEN(JW)                                                              \
            { *(half8*)(awbase + ((ajoff * 2 +  0) ^ awsz)) = pre[JW][0] * civ; \
              *(half8*)(awbase + ((ajoff * 2 + 16) ^ awsz)) = pre[JW][1] * civ; \
              *(half8*)(awbase + ((ajoff * 2 + 32) ^ awsz)) = pre[JW][2] * civ; \
              *(half8*)(awbase + ((ajoff * 2 + 48) ^ awsz)) = pre[JW][3] * civ; }
            switch (ujw_c) {
                case 0:  AGEN(0); break;
                case 1:  AGEN(1); break;
                case 2:  AGEN(2); break;
                default: AGEN(3); break;
            }
#undef AGEN
        }

        // ---- pipeline next tile's ci scalar (1 vmem op, L1-resident) ----
        if (more) {
            int ui_n, ujw_n;
            unit_decode(t0 + it + 1, ui_n, ujw_n);
            ujw_c = ujw_n;            // A-gen(it) already consumed old value
            ci_c = crow[ui_n];
        }

        // ---- barrier1: counted vmcnt (never 0 mid-loop) + lgkm drain ----
        if (more) asm volatile("s_waitcnt vmcnt(5) lgkmcnt(0)" ::: "memory");
        else      asm volatile("s_waitcnt vmcnt(0) lgkmcnt(0)" ::: "memory");
        __builtin_amdgcn_s_barrier();
        __builtin_amdgcn_sched_barrier(0);

        // ---- MFMA: 2 k-steps of 32, 4x4 16x16 tiles per wave ----
        __builtin_amdgcn_s_setprio(1);
#pragma unroll
        for (int kh = 0; kh < 2; ++kh) {
            half8 af[4], bfr[4];
#pragma unroll
            for (int i = 0; i < 4; ++i) {
                const int r = wrow + i * 16 + l15;
                const int cb = (kh * 64 + l4 * 16) ^ ((r & 7) << 4);
                af[i] = *(const half8*)((const char*)Al + r * 128 + cb);
            }
            const int s = ((kh * 4 + l4) ^ l7) * 8;
#pragma unroll
            for (int j = 0; j < 4; ++j)
                bfr[j] = *(const half8*)&Bl[cur][wcol + j * 16 + l15][s];
#pragma unroll
            for (int i = 0; i < 4; ++i)
#pragma unroll
                for (int j = 0; j < 4; ++j)
                    acc[i][j] = __builtin_amdgcn_mfma_f32_16x16x32_f16(
                        af[i], bfr[j], acc[i][j], 0, 0, 0);
        }
        __builtin_amdgcn_s_setprio(0);

        // ---- barrier2: A/B reuse guard (no vmcnt drain needed) ----
        __builtin_amdgcn_sched_barrier(0);
        __builtin_amdgcn_s_barrier();
    }

    // epilogue: C/D layout col=lane&15, row=(lane>>4)*4+r (m89-verified)
    _Float16* outp = hidpart + (size_t)ks * BATCH * P_HID;
    const int r0 = m0 + wrow + l4 * 4;
    const int c0 = n0 + wcol + l15;
#pragma unroll
    for (int i = 0; i < 4; ++i)
#pragma unroll
        for (int j = 0; j < 4; ++j)
#pragma unroll
            for (int r = 0; r < 4; ++r)
                outp[(size_t)(r0 + i * 16 + r) * P_HID + c0 + j * 16] =
                    (_Float16)acc[i][j][r];
}

// ---------------------------------------------------------------------------
// Kernel 3: sum k-splits + pb1, ReLU, dot with pw2, +pb2, sigmoid -> f32 out
// R12: ALL 4 waves participate in the final dot (was wave-0-only: 75% idle);
// each wave handles 2 of the 8 k-slots, then a 4-entry LDS reduce.
// ---------------------------------------------------------------------------
__global__ __launch_bounds__(256) void finalize(
    const _Float16* __restrict__ hidpart,
    const float* __restrict__ pb1,
    const float* __restrict__ pw2,
    const float* __restrict__ pb2,
    float* __restrict__ out)
{
    const int b = blockIdx.x, t = threadIdx.x;
    const int wv = t >> 6, lane = t & 63;

    float acc[8];
#pragma unroll
    for (int k = 0; k < 8; ++k) acc[k] = 0.f;

    // wave wv handles splits {wv, wv+4, wv+8}; lane owns 8 consec n
#pragma unroll
    for (int si = 0; si < 3; ++si) {
        const int s = wv + 4 * si;
        const half8 v = *(const half8*)(hidpart + (size_t)s * BATCH * P_HID
                                        + (size_t)b * P_HID + lane * 8);
#pragma unroll
        for (int k = 0; k < 8; ++k) acc[k] += (float)v[k];
    }

    __shared__ float red[4 * 512];   // [wave][k*64+lane]
#pragma unroll
    for (int k = 0; k < 8; ++k) red[wv * 512 + k * 64 + lane] = acc[k];
    __syncthreads();

    // all waves: wave wv covers k-slots {2wv, 2wv+1}
    float dotw = 0.f;
#pragma unroll
    for (int kk = 0; kk < 2; ++kk) {
        const int k = wv * 2 + kk;
        const int n = lane * 8 + k;
        float v = red[k * 64 + lane] + red[512 + k * 64 + lane]
                + red[1024 + k * 64 + lane] + red[1536 + k * 64 + lane];
        v += pb1[n];
        v = fmaxf(v, 0.f);
        dotw += v * pw2[n];
    }
#pragma unroll
    for (int off = 32; off; off >>= 1) dotw += __shfl_down(dotw, off, 64);

    __shared__ float r2[4];
    if (lane == 0) r2[wv] = dotw;
    __syncthreads();
    if (t == 0) {
        const float s = r2[0] + r2[1] + r2[2] + r2[3] + pb2[0];
        out[b] = 1.f / (1.f + expf(-s));
    }
}

extern "C" void kernel_launch(void* const* d_in, const int* in_sizes, int n_in,
                              void* d_out, int out_size, void* d_ws, size_t ws_size,
                              hipStream_t stream)
{
    const float* dense  = (const float*)d_in[0];
    const int*   sparse = (const int*)d_in[1];
    // d_in[2] tokenizers == arange(CARD): gather index is the sparse value itself
    const float* emb = (const float*)d_in[3];
    const float* dw1 = (const float*)d_in[4];
    const float* db1 = (const float*)d_in[5];
    const float* dw2 = (const float*)d_in[6];
    const float* db2 = (const float*)d_in[7];
    const float* sw1 = (const float*)d_in[8];
    const float* sb1 = (const float*)d_in[9];
    const float* sw2 = (const float*)d_in[10];
    const float* sb2 = (const float*)d_in[11];
    const float* pw1 = (const float*)d_in[12];
    const float* pb1 = (const float*)d_in[13];
    const float* pw2 = (const float*)d_in[14];
    const float* pb2 = (const float*)d_in[15];

    char* ws = (char*)d_ws;
    _Float16* cbf     = (_Float16*)ws;                                   // 1 MB
    _Float16* St      = (_Float16*)(ws + (1 << 20));                     // 40 MB
    _Float16* hidpart = (_Float16*)(ws + (1 << 20) + ((size_t)40 << 20)); // 24 MB (12 splits)

    fused_pre<<<PREP_BLOCKS + BATCH / 4, 256, 0, stream>>>(
        dense, sparse, emb, dw1, db1, dw2, db2, sw1, sb1, sw2, sb2, pw1,
        cbf, St);
    bilinear_gemm<<<16 * 4 * KSPLIT, 256, 0, stream>>>(cbf, St, hidpart);
    finalize<<<BATCH, 256, 0, stream>>>(hidpart, pb1, pw2, pb2, (float*)d_out);
}

// Round 13
// 352.259 us; speedup vs baseline: 1.0731x; 1.0070x over previous
//
#include <hip/hip_runtime.h>
#include <hip/hip_fp16.h>
#include <math.h>

#define BATCH 2048
#define NFEAT 7
#define CARD 10000
#define CONCAT 256
#define P_HID 512

#define BM 128
#define BN 128
#define BK 64
#define KSPLIT 8              // 512 blocks = exactly 2 per CU (64 KB LDS each)
#define NTILES 80             // 640 / 8
#define NUNITS 640            // triangle-packed (i, j-window) units
#define UNIT_ST (512 * 64)    // fp16 elements per unit in blocked St layout
#define PREP_BLOCKS (NUNITS * 2)   // one block per (unit, n-half)

using f16x4   = __attribute__((ext_vector_type(4))) _Float16;
using half8   = __attribute__((ext_vector_type(8))) _Float16;
using floatx4 = __attribute__((ext_vector_type(4))) float;

// async global->LDS DMA, 16 B per lane; LDS dest = wave-uniform base + lane*16
__device__ __forceinline__ void dma16(const _Float16* g, _Float16* l) {
    __builtin_amdgcn_global_load_lds(
        (const __attribute__((address_space(1))) unsigned int*)g,
        (__attribute__((address_space(3))) unsigned int*)l,
        16, 0, 0);
}

// unit u -> (i, jw): pairs (i, j) with j in [jw*64, jw*64+64).
// u<256: diagonal-window units, i=u, jw=i>>6 (entries j<i zeroed in B).
// u>=256: full units, ordered by i with jw > i>>6.
__device__ __forceinline__ void unit_decode(int u, int& i, int& jw) {
    if (u < 256)      { i = u;                jw = u >> 6; }
    else if (u < 448) { int v = u - 256; i = v / 3;        jw = 1 + v % 3; }
    else if (u < 576) { int v = u - 448; i = 64 + (v >> 1); jw = 2 + (v & 1); }
    else              { i = 128 + (u - 576); jw = 3; }
}

// ---------------------------------------------------------------------------
// Kernel 1 (fused pre): R10 version verbatim (best-measured total config).
// ---------------------------------------------------------------------------
__global__ __launch_bounds__(256) void fused_pre(
    const float* __restrict__ dense, const int* __restrict__ sparse,
    const float* __restrict__ emb,
    const float* __restrict__ dw1, const float* __restrict__ db1,
    const float* __restrict__ dw2, const float* __restrict__ db2,
    const float* __restrict__ sw1, const float* __restrict__ sb1,
    const float* __restrict__ sw2, const float* __restrict__ sb2,
    const float* __restrict__ pw1,
    _Float16* __restrict__ cbf, _Float16* __restrict__ St)
{
    __shared__ __align__(16) _Float16 sh[64 * 256];   // 32 KB
    const int tid = threadIdx.x;

    if (blockIdx.x < PREP_BLOCKS) {
        const int u = blockIdx.x >> 1, nh = blockIdx.x & 1;
        const int nb = nh * 256;
        int i, jw;
        unit_decode(u, i, jw);

        // ---- fill: 64 q-rows x 256 n, fp32 sum -> fp16 in LDS ----
#pragma unroll
        for (int m = 0; m < 16; ++m) {
            const int flat = m * 256 + tid;       // [0, 4096)
            const int q = flat >> 6, c4 = flat & 63;
            const int j = (jw << 6) + q;
            floatx4 s = {0.f, 0.f, 0.f, 0.f};
            if (j >= i) {
                s = __builtin_nontemporal_load(
                    (const floatx4*)(pw1 + ((size_t)i * 256 + j) * P_HID + nb + 4 * c4));
                if (j > i) {
                    const floatx4 mv = __builtin_nontemporal_load(
                        (const floatx4*)(pw1 + ((size_t)j * 256 + i) * P_HID + nb + 4 * c4));
                    s += mv;
                }
            }
            f16x4 hv = {(_Float16)s.x, (_Float16)s.y, (_Float16)s.z, (_Float16)s.w};
            *(f16x4*)(sh + q * 256 + 4 * c4) = hv;   // conflict-free
        }
        __syncthreads();

        // ---- transpose + store: thread t owns n-column (nb + t) ----
        const _Float16* col = sh + tid;
        _Float16* outp = St + (size_t)u * UNIT_ST + (size_t)(nb + tid) * 64;
#pragma unroll
        for (int e = 0; e < 8; ++e) {
            half8 o;
#pragma unroll
            for (int r = 0; r < 8; ++r) o[r] = col[(8 * e + r) * 256];
            *(half8*)(outp + 8 * e) = o;
        }
    } else {
        // ---- concat build: 4 batch rows per block, one wave per row ----
        float* smem = (float*)sh;
        const int wv = tid >> 6, t = tid & 63;
        const int b = (blockIdx.x - PREP_BLOCKS) * 4 + wv;
        float* xs   = smem + wv * 13;
        float* bufA = smem + 64  + wv * 64;
        float* bufB = smem + 320 + wv * 64;

        if (t < 13) xs[t] = dense[b * 13 + t];
        __syncthreads();

        float h = db1[t];
#pragma unroll
        for (int d = 0; d < 13; ++d) h += xs[d] * dw1[d * 64 + t];
        bufA[t] = fmaxf(h, 0.f);
        __syncthreads();

        if (t < 32) {
            float o = db2[t];
#pragma unroll
            for (int k = 0; k < 64; ++k) o += bufA[k] * dw2[k * 32 + t];
            cbf[b * 256 + t] = (_Float16)o;
        }

        for (int f = 0; f < NFEAT; ++f) {
            __syncthreads();
            const int idx = sparse[b * NFEAT + f];
            bufB[t] = emb[((size_t)(f * CARD + idx)) * 64 + t];
            __syncthreads();
            float s = sb1[f * 64 + t];
#pragma unroll
            for (int e = 0; e < 64; ++e) s += bufB[e] * sw1[(f * 64 + e) * 64 + t];
            bufA[t] = fmaxf(s, 0.f);
            __syncthreads();
            if (t < 32) {
                float o = sb2[f * 32 + t];
#pragma unroll
                for (int k = 0; k < 64; ++k) o += bufA[k] * sw2[(f * 64 + k) * 32 + t];
                cbf[b * 256 + 32 + f * 32 + t] = (_Float16)o;
            }
        }
    }
}

// ---------------------------------------------------------------------------
// Kernel 2: hidden[b,n] = sum over packed pairs A[b,k] * St[n,k].
// fp16 GEMM M=2048 N=512 K=40960.
// R13: R10 structure with A ALSO double-buffered -> ONE barrier per tile
// (R10 paid 2), and A-gen(it+1) overlapping MFMA(it) in the same phase.
// 64 KB LDS -> 2 blocks/CU (midpoint between R10's 3 and R11's failed 1).
// Per-CU work identical to R10 (160 tile-rounds); barriers halved (320->160).
// vmcnt: in-loop wait vmcnt(1) drains dma(it+1) x4, leaves pipelined ci;
// vmcnt(0) only at it=NTILES-2 (ci pipeline empty). All buffer hazards are
// sealed by the previous barrier (writes always target cur^1).
// ---------------------------------------------------------------------------
__global__ __launch_bounds__(256, 2) void bilinear_gemm(
    const _Float16* __restrict__ cbf, const _Float16* __restrict__ St,
    _Float16* __restrict__ hidpart)
{
    __shared__ __align__(16) _Float16 Al[2][BM * BK];  // 2 x 16 KB, XOR-swz
    __shared__ _Float16 Bl[2][BN][BK];                 // 2 x 16 KB, XOR-swz

    // XCD-aware decode (512 blocks, %8==0 -> bijective)
    const int b = blockIdx.x;
    const int xcd = b & 7, slot = b >> 3;         // slot 0..63
    const int mt = slot & 15;
    const int slice = ((slot >> 4) << 3) | xcd;   // 0..31
    const int nt = slice & 3, ks = slice >> 2;    // nt 0..3, ks 0..7
    const int m0 = mt * BM, n0 = nt * BN;
    const int t0 = ks * NTILES;

    const int tid = threadIdx.x, lane = tid & 63, wv = tid >> 6;
    const int wrow = (wv & 1) * 64, wcol = (wv >> 1) * 64;
    const int l15 = lane & 15, l4 = lane >> 4, l7 = lane & 7;
    const int arow = tid >> 1, ajoff = (tid & 1) * 32;  // A-gen: 2 thr/row

    floatx4 acc[4][4];
#pragma unroll
    for (int i = 0; i < 4; ++i)
#pragma unroll
        for (int j = 0; j < 4; ++j) acc[i][j] = (floatx4){0.f, 0.f, 0.f, 0.f};

    const _Float16* crow = cbf + (m0 + arow) * 256;

    // ---- hoisted window preload: all 4 possible jw windows (64 VGPR) ----
    half8 pre[4][4];
#pragma unroll
    for (int jw = 0; jw < 4; ++jw)
#pragma unroll
        for (int x = 0; x < 4; ++x)
            pre[jw][x] = *(const half8*)(crow + (jw << 6) + ajoff + 8 * x);

    const int awsz = (arow & 7) << 4;   // A XOR swizzle (write side)

    // A-gen: pre[JW] * C -> Al[NB] (swizzled packed 128 B rows)
#define AGEN(NB, JW, C)                                                        \
    {                                                                          \
        const half8 civ_ = {C, C, C, C, C, C, C, C};                           \
        char* aw_ = (char*)Al[NB] + arow * 128;                                \
        *(half8*)(aw_ + ((ajoff * 2 +  0) ^ awsz)) = pre[JW][0] * civ_;        \
        *(half8*)(aw_ + ((ajoff * 2 + 16) ^ awsz)) = pre[JW][1] * civ_;        \
        *(half8*)(aw_ + ((ajoff * 2 + 32) ^ awsz)) = pre[JW][2] * civ_;        \
        *(half8*)(aw_ + ((ajoff * 2 + 48) ^ awsz)) = pre[JW][3] * civ_;        \
    }
#define AGEN_SW(NB, JW, C)                                                     \
    switch (JW) {                                                              \
        case 0:  AGEN(NB, 0, C); break;                                        \
        case 1:  AGEN(NB, 1, C); break;                                        \
        case 2:  AGEN(NB, 2, C); break;                                        \
        default: AGEN(NB, 3, C); break;                                        \
    }

    // B staging source (pre-swizzled per-lane global address, blocked St)
    const int drow = wv * 32 + (lane >> 3);
    const int eswz = (lane & 7) ^ ((lane >> 3) & 7);
    const _Float16* bsrc = St + (size_t)t0 * UNIT_ST + (size_t)(n0 + drow) * 64 + eswz * 8;

    // ---- prologue: build tile 0 (B dma + A-gen), pipeline ci(1) ----
    {
        int ui0, ujw0; unit_decode(t0, ui0, ujw0);
        const _Float16 ci0 = crow[ui0];           // vm: ci0
#pragma unroll
        for (int p = 0; p < 4; ++p)               // vm: dma0 x4
            dma16(bsrc + (size_t)(p * 8) * 64, &Bl[0][wv * 32 + p * 8][0]);
        bsrc += UNIT_ST;
        AGEN_SW(0, ujw0, ci0);                    // waits ci0 (vmcnt(4))
    }
    int ujw_n;
    _Float16 ci_n;
    {
        int ui1, j1; unit_decode(t0 + 1, ui1, j1);
        ujw_n = j1;
        ci_n = crow[ui1];                         // vm: ci1 (stays in flight)
    }
    asm volatile("s_waitcnt vmcnt(1) lgkmcnt(0)" ::: "memory");  // dma0 done
    __builtin_amdgcn_s_barrier();
    __builtin_amdgcn_sched_barrier(0);

    for (int it = 0; it < NTILES; ++it) {
        const int cur = it & 1;
        const bool more1 = (it + 1 < NTILES);
        const bool more2 = (it + 2 < NTILES);

        // ---- stage tile it+1 into buffers cur^1 (overlaps MFMA below) ----
        if (more1) {
#pragma unroll
            for (int p = 0; p < 4; ++p)
                dma16(bsrc + (size_t)(p * 8) * 64, &Bl[cur ^ 1][wv * 32 + p * 8][0]);
            bsrc += UNIT_ST;
            AGEN_SW(cur ^ 1, ujw_n, ci_n);        // waits ci(it+1): vmcnt(4)
        }
        // ---- pipeline ci(it+2) ----
        if (more2) {
            int ui2, j2; unit_decode(t0 + it + 2, ui2, j2);
            ujw_n = j2;
            ci_n = crow[ui2];
        }

        // ---- MFMA(it) on Al[cur], Bl[cur] (A-gen/dma above co-scheduled) ----
        __builtin_amdgcn_s_setprio(1);
#pragma unroll
        for (int kh = 0; kh < 2; ++kh) {
            half8 af[4], bfr[4];
#pragma unroll
            for (int i = 0; i < 4; ++i) {
                const int r = wrow + i * 16 + l15;
                const int cb = (kh * 64 + l4 * 16) ^ ((r & 7) << 4);
                af[i] = *(const half8*)((const char*)Al[cur] + r * 128 + cb);
            }
            const int s = ((kh * 4 + l4) ^ l7) * 8;
#pragma unroll
            for (int j = 0; j < 4; ++j)
                bfr[j] = *(const half8*)&Bl[cur][wcol + j * 16 + l15][s];
#pragma unroll
            for (int i = 0; i < 4; ++i)
#pragma unroll
                for (int j = 0; j < 4; ++j)
                    acc[i][j] = __builtin_amdgcn_mfma_f32_16x16x32_f16(
                        af[i], bfr[j], acc[i][j], 0, 0, 0);
        }
        __builtin_amdgcn_s_setprio(0);

        // ---- ONE barrier per tile: seal dma(it+1) + A-gen(it+1) ----
        if (more1) {
            if (more2)
                asm volatile("s_waitcnt vmcnt(1) lgkmcnt(0)" ::: "memory");
            else   // ci pipeline empty: dma(it+1) is all that's outstanding
                asm volatile("s_waitcnt vmcnt(0) lgkmcnt(0)" ::: "memory");
            __builtin_amdgcn_s_barrier();
            __builtin_amdgcn_sched_barrier(0);
        }
    }
#undef AGEN_SW
#undef AGEN

    // epilogue: C/D layout col=lane&15, row=(lane>>4)*4+r (m89-verified)
    _Float16* outp = hidpart + (size_t)ks * BATCH * P_HID;
    const int r0 = m0 + wrow + l4 * 4;
    const int c0 = n0 + wcol + l15;
#pragma unroll
    for (int i = 0; i < 4; ++i)
#pragma unroll
        for (int j = 0; j < 4; ++j)
#pragma unroll
            for (int r = 0; r < 4; ++r)
                outp[(size_t)(r0 + i * 16 + r) * P_HID + c0 + j * 16] =
                    (_Float16)acc[i][j][r];
}

// ---------------------------------------------------------------------------
// Kernel 3: sum k-splits + pb1, ReLU, dot with pw2, +pb2, sigmoid -> f32 out
// All 4 waves in the final dot; wave wv covers k-slots {2wv, 2wv+1}.
// ---------------------------------------------------------------------------
__global__ __launch_bounds__(256) void finalize(
    const _Float16* __restrict__ hidpart,
    const float* __restrict__ pb1,
    const float* __restrict__ pw2,
    const float* __restrict__ pb2,
    float* __restrict__ out)
{
    const int b = blockIdx.x, t = threadIdx.x;
    const int wv = t >> 6, lane = t & 63;

    float acc[8];
#pragma unroll
    for (int k = 0; k < 8; ++k) acc[k] = 0.f;

    // wave wv handles splits {wv, wv+4}; lane owns 8 consec n
#pragma unroll
    for (int si = 0; si < 2; ++si) {
        const int s = wv + 4 * si;
        const half8 v = *(const half8*)(hidpart + (size_t)s * BATCH * P_HID
                                        + (size_t)b * P_HID + lane * 8);
#pragma unroll
        for (int k = 0; k < 8; ++k) acc[k] += (float)v[k];
    }

    __shared__ float red[4 * 512];   // [wave][k*64+lane]
#pragma unroll
    for (int k = 0; k < 8; ++k) red[wv * 512 + k * 64 + lane] = acc[k];
    __syncthreads();

    float dotw = 0.f;
#pragma unroll
    for (int kk = 0; kk < 2; ++kk) {
        const int k = wv * 2 + kk;
        const int n = lane * 8 + k;
        float v = red[k * 64 + lane] + red[512 + k * 64 + lane]
                + red[1024 + k * 64 + lane] + red[1536 + k * 64 + lane];
        v += pb1[n];
        v = fmaxf(v, 0.f);
        dotw += v * pw2[n];
    }
#pragma unroll
    for (int off = 32; off; off >>= 1) dotw += __shfl_down(dotw, off, 64);

    __shared__ float r2[4];
    if (lane == 0) r2[wv] = dotw;
    __syncthreads();
    if (t == 0) {
        const float s = r2[0] + r2[1] + r2[2] + r2[3] + pb2[0];
        out[b] = 1.f / (1.f + expf(-s));
    }
}

extern "C" void kernel_launch(void* const* d_in, const int* in_sizes, int n_in,
                              void* d_out, int out_size, void* d_ws, size_t ws_size,
                              hipStream_t stream)
{
    const float* dense  = (const float*)d_in[0];
    const int*   sparse = (const int*)d_in[1];
    // d_in[2] tokenizers == arange(CARD): gather index is the sparse value itself
    const float* emb = (const float*)d_in[3];
    const float* dw1 = (const float*)d_in[4];
    const float* db1 = (const float*)d_in[5];
    const float* dw2 = (const float*)d_in[6];
    const float* db2 = (const float*)d_in[7];
    const float* sw1 = (const float*)d_in[8];
    const float* sb1 = (const float*)d_in[9];
    const float* sw2 = (const float*)d_in[10];
    const float* sb2 = (const float*)d_in[11];
    const float* pw1 = (const float*)d_in[12];
    const float* pb1 = (const float*)d_in[13];
    const float* pw2 = (const float*)d_in[14];
    const float* pb2 = (const float*)d_in[15];

    char* ws = (char*)d_ws;
    _Float16* cbf     = (_Float16*)ws;                                   // 1 MB
    _Float16* St      = (_Float16*)(ws + (1 << 20));                     // 40 MB
    _Float16* hidpart = (_Float16*)(ws + (1 << 20) + ((size_t)40 << 20)); // 16 MB (8 splits)

    fused_pre<<<PREP_BLOCKS + BATCH / 4, 256, 0, stream>>>(
        dense, sparse, emb, dw1, db1, dw2, db2, sw1, sb1, sw2, sb2, pw1,
        cbf, St);
    bilinear_gemm<<<16 * 4 * KSPLIT, 256, 0, stream>>>(cbf, St, hidpart);
    finalize<<<BATCH, 256, 0, stream>>>(hidpart, pb1, pw2, pb2, (float*)d_out);
}